// Round 13
// baseline (252.058 us; speedup 1.0000x reference)
//
#include <hip/hip_runtime.h>
#include <hip/hip_bf16.h>

typedef unsigned short u16;
typedef __attribute__((ext_vector_type(8))) short bf16x8;
typedef __attribute__((ext_vector_type(4))) float f32x4;
typedef __attribute__((ext_vector_type(4))) int i32x4;

#define HEADS 4
#define OUT_DIM 64
#define HF 256          // HEADS*OUT_DIM
#define IN_DIM 128
#define NEG_SLOPE 0.2f
#define EPSF 1e-16f

__device__ __forceinline__ float braw2f(u16 u) {
    union { float f; unsigned int i; } c; c.i = ((unsigned int)u) << 16; return c.f;
}
__device__ __forceinline__ u16 f2braw(float v) {
    __hip_bfloat16 t = __float2bfloat16(v);
    return *(u16*)&t;
}
__device__ __forceinline__ float lrelu(float e) { return e < 0.f ? NEG_SLOPE * e : e; }

// edge_index contract says int32; defend against raw int64 (odd words all-zero).
__device__ __forceinline__ bool detect_i64(const int* ei) {
    return (ei[1] | ei[3] | ei[5] | ei[7] | ei[9] | ei[11] | ei[13] | ei[15]) == 0;
}

// ---------- init: fold wa = W*att only (zeroing via hipMemsetAsync) ----
__global__ __launch_bounds__(256) void init_kernel(const float* __restrict__ W,
                                                   const float* __restrict__ att_s,
                                                   const float* __restrict__ att_d,
                                                   float* __restrict__ wa_s,
                                                   float* __restrict__ wa_d) {
    for (int idx = threadIdx.x; idx < HEADS * IN_DIM; idx += 256) {
        int h = idx >> 7, k = idx & 127;
        float ss = 0.f, sd = 0.f;
        for (int f = 0; f < OUT_DIM; ++f) {
            float wv = W[k * HF + h * OUT_DIM + f];
            ss = fmaf(wv, att_s[h * OUT_DIM + f], ss);
            sd = fmaf(wv, att_d[h * OUT_DIM + f], sd);
        }
        wa_s[idx] = ss;
        wa_d[idx] = sd;
    }
}

// ---------- phase1: [0,NA) logits + x->bf16 | [NA,NA+NC) count | tail Wfrag ----
// Count (real edges only; self-loops are handled inline in gather): 4-way
// replicated counters; atomic's return value + decoded edge recorded in ONE
// 16-B nontemporal einfo record, so fill needs no atomic / no re-decode.
__global__ __launch_bounds__(256) void phase1_kernel(const float* __restrict__ x,
                                                     const int* __restrict__ ei,
                                                     const float* __restrict__ W,
                                                     const float* __restrict__ wa_s,
                                                     const float* __restrict__ wa_d,
                                                     float* __restrict__ a_src,
                                                     float* __restrict__ a_dst,
                                                     u16* __restrict__ xb,
                                                     u16* __restrict__ Wfrag,
                                                     int* __restrict__ cnt4,
                                                     int* __restrict__ einfo,
                                                     int N, int E, int NA, int NC) {
    int b = blockIdx.x;
    if (b < NA) {
        int wid = threadIdx.x >> 6;
        int l = threadIdx.x & 63;
        int g = l >> 4, c = l & 15, kc = c * 8;
        int v = b * 16 + wid * 4 + g;
        if (v >= N) return;

        const float4* xr = (const float4*)(x + (size_t)v * IN_DIM + kc);
        float4 x0 = xr[0], x1 = xr[1];

        uint4 u;
        u.x = (unsigned)f2braw(x0.x) | ((unsigned)f2braw(x0.y) << 16);
        u.y = (unsigned)f2braw(x0.z) | ((unsigned)f2braw(x0.w) << 16);
        u.z = (unsigned)f2braw(x1.x) | ((unsigned)f2braw(x1.y) << 16);
        u.w = (unsigned)f2braw(x1.z) | ((unsigned)f2braw(x1.w) << 16);
        *(uint4*)(xb + (size_t)v * IN_DIM + kc) = u;

        float ps[4], pd[4];
        #pragma unroll
        for (int h = 0; h < 4; ++h) {
            const float4* s4 = (const float4*)(wa_s + h * IN_DIM + kc);
            const float4* d4 = (const float4*)(wa_d + h * IN_DIM + kc);
            float4 s0 = s4[0], s1 = s4[1], d0 = d4[0], d1 = d4[1];
            ps[h] = x0.x*s0.x + x0.y*s0.y + x0.z*s0.z + x0.w*s0.w
                  + x1.x*s1.x + x1.y*s1.y + x1.z*s1.z + x1.w*s1.w;
            pd[h] = x0.x*d0.x + x0.y*d0.y + x0.z*d0.z + x0.w*d0.w
                  + x1.x*d1.x + x1.y*d1.y + x1.z*d1.z + x1.w*d1.w;
        }
        #pragma unroll
        for (int off = 1; off < 16; off <<= 1) {
            #pragma unroll
            for (int h = 0; h < 4; ++h) {
                ps[h] += __shfl_xor(ps[h], off);
                pd[h] += __shfl_xor(pd[h], off);
            }
        }
        if (c == 0) {
            float4 vs, vd;
            vs.x = ps[0]; vs.y = ps[1]; vs.z = ps[2]; vs.w = ps[3];
            vd.x = pd[0]; vd.y = pd[1]; vd.z = pd[2]; vd.w = pd[3];
            *(float4*)(a_src + (size_t)v * HEADS) = vs;
            *(float4*)(a_dst + (size_t)v * HEADS) = vd;
        }
    } else if (b < NA + NC) {
        int t = (b - NA) * 256 + threadIdx.x;
        if (t >= E) return;                 // self-loops handled inline in gather
        bool i64 = detect_i64(ei);
        int src, dst;
        if (i64) { src = ei[2 * t]; dst = ei[2 * (E + t)]; }
        else     { src = ei[t];     dst = ei[E + t]; }
        bool ok = (src >= 0 && src < N && dst >= 0 && dst < N);
        int pos = 0;
        if (ok) pos = atomicAdd(cnt4 + (t & 3) * N + dst, 1);
        if (einfo) {
            i32x4 rec;
            rec.x = ok ? src : -1;
            rec.y = ok ? dst : 0;
            rec.z = pos;
            rec.w = 0;
            __builtin_nontemporal_store(rec, (i32x4*)(einfo + 4 * (size_t)t));
        }
    } else {
        int bb = b - NA - NC;   // 8 blocks
        for (int idx = bb * 256 + threadIdx.x; idx < 32768; idx += 8 * 256) {
            int j = idx & 7, l = (idx >> 3) & 63, t = (idx >> 9) & 3;
            int s = (idx >> 11) & 3, h = (idx >> 13) & 3;
            int k = s * 32 + ((l >> 4) & 3) * 8 + j;
            int col = h * OUT_DIM + t * 16 + (l & 15);
            Wfrag[idx] = f2braw(W[k * HF + col]);
        }
    }
}

// ---------- order-free offsets + degree histogram + replica bases ----------
__global__ __launch_bounds__(256) void offset_kernel(int* __restrict__ cnt4,
                                                     int* __restrict__ offs,
                                                     int* __restrict__ gcnt,
                                                     int* __restrict__ hist, int N) {
    __shared__ int lh[256];
    lh[threadIdx.x] = 0;
    __syncthreads();

    int idx = blockIdx.x * 256 + threadIdx.x;
    int l = threadIdx.x & 63;
    int d = 0;
    if (idx < N) {
        int c0 = cnt4[idx];
        int c1 = cnt4[N + idx];
        int c2 = cnt4[2 * N + idx];
        int c3 = cnt4[3 * N + idx];
        d = c0 + c1 + c2 + c3;
        cnt4[idx] = d;
        cnt4[N + idx] = c0;
        cnt4[2 * N + idx] = c0 + c1;
        cnt4[3 * N + idx] = c0 + c1 + c2;
        atomicAdd(lh + min(max(d, 0), 255), 1);
    }

    int s = d;
    #pragma unroll
    for (int off = 1; off < 64; off <<= 1) {
        int t = __shfl_up(s, off);
        if (l >= off) s += t;
    }
    int base = 0;
    if (l == 63) base = atomicAdd(gcnt, s);
    base = __shfl(base, 63);
    if (idx < N) offs[idx] = base + s - d;

    __syncthreads();
    if (lh[threadIdx.x]) atomicAdd(hist + threadIdx.x, lh[threadIdx.x]);
}

// ---------- fused fill + scatter ----------
// Fill: atomic-free on the einfo path (one NT 16-B load per edge); writes one
// NT 16-B eslots record per edge. Real edges only (t < E).
__global__ __launch_bounds__(256) void fillscatter_kernel(const int* __restrict__ ei,
                                                          const int* __restrict__ offs,
                                                          int* __restrict__ cur,
                                                          int* __restrict__ slots,
                                                          unsigned* __restrict__ eslots,
                                                          const float* __restrict__ a_src,
                                                          const float* __restrict__ a_dst,
                                                          const int* __restrict__ cnt4,
                                                          const int* __restrict__ hist,
                                                          int* __restrict__ bcur,
                                                          int* __restrict__ perm,
                                                          const int* __restrict__ einfo,
                                                          int E, int N, int NC) {
    __shared__ int sc[256];
    __shared__ int lh[256];
    __shared__ int lbase[256];

    int b = blockIdx.x;
    if (b < NC) {
        // ---- fill ----
        int t = b * 256 + threadIdx.x;
        if (t >= E) return;
        int src, dst, idx;
        if (einfo) {
            i32x4 rec = __builtin_nontemporal_load((const i32x4*)(einfo + 4 * (size_t)t));
            src = rec.x; dst = rec.y;
            if (src < 0) return;
            int r = t & 3;
            int base = (r == 0) ? 0 : cnt4[r * N + dst];
            idx = offs[dst] + base + rec.z;
        } else {
            bool i64 = detect_i64(ei);
            if (i64) { src = ei[2 * t]; dst = ei[2 * (E + t)]; }
            else     { src = ei[t];     dst = ei[E + t]; }
            if (!(src >= 0 && src < N && dst >= 0 && dst < N)) return;
            int pos = atomicAdd(cur + dst, 1);
            idx = offs[dst] + pos;
        }
        if (eslots) {
            float4 as = ((const float4*)a_src)[src];
            float4 ad = ((const float4*)a_dst)[dst];
            float w0 = __expf(lrelu(as.x + ad.x));
            float w1 = __expf(lrelu(as.y + ad.y));
            float w2 = __expf(lrelu(as.z + ad.z));
            float w3 = __expf(lrelu(as.w + ad.w));
            i32x4 rec;
            rec.x = src;
            rec.y = (int)((unsigned)f2braw(w0) | ((unsigned)f2braw(w1) << 16));
            rec.z = (int)((unsigned)f2braw(w2) | ((unsigned)f2braw(w3) << 16));
            rec.w = 0;
            __builtin_nontemporal_store(rec, (i32x4*)(eslots + 4 * (size_t)idx));
        } else {
            slots[idx] = src;
        }
    } else {
        // ---- scatter (with in-block hist scan) ----
        int tid = threadIdx.x;
        sc[tid] = hist[tid];
        lh[tid] = 0;
        __syncthreads();
        #pragma unroll
        for (int off = 1; off < 256; off <<= 1) {
            int tv = (tid >= off) ? sc[tid - off] : 0;
            __syncthreads();
            sc[tid] += tv;
            __syncthreads();
        }

        int idx = (b - NC) * 256 + tid;
        int bk = 0, mypos = 0;
        bool valid = (idx < N);
        if (valid) {
            bk = min(max(cnt4[idx], 0), 255);
            mypos = atomicAdd(lh + bk, 1);
        }
        __syncthreads();
        int c = lh[tid];
        if (c) lbase[tid] = atomicAdd(bcur + tid, c);
        __syncthreads();
        if (valid) {
            int p = (N - sc[bk]) + lbase[bk] + mypos;
            if (p >= 0 && p < N) perm[p] = idx;
        }
    }
}

// accumulate one edge (packed bf16 weights) into the 4-head G registers
#define ACC_EDGE(w01, w23, r) do { \
    float w0_ = braw2f((w01) & 0xffff), w1_ = braw2f((unsigned)(w01) >> 16); \
    float w2_ = braw2f((w23) & 0xffff), w3_ = braw2f((unsigned)(w23) >> 16); \
    ls0 += w0_; ls1 += w1_; ls2 += w2_; ls3 += w3_; \
    float xv_[8]; \
    xv_[0] = braw2f((r).x & 0xffff); xv_[1] = braw2f((r).x >> 16); \
    xv_[2] = braw2f((r).y & 0xffff); xv_[3] = braw2f((r).y >> 16); \
    xv_[4] = braw2f((r).z & 0xffff); xv_[5] = braw2f((r).z >> 16); \
    xv_[6] = braw2f((r).w & 0xffff); xv_[7] = braw2f((r).w >> 16); \
    _Pragma("unroll") \
    for (int q_ = 0; q_ < 8; ++q_) { \
        G0[q_] = fmaf(w0_, xv_[q_], G0[q_]); \
        G1[q_] = fmaf(w1_, xv_[q_], G1[q_]); \
        G2[q_] = fmaf(w2_, xv_[q_], G2[q_]); \
        G3[q_] = fmaf(w3_, xv_[q_], G3[q_]); \
    } \
} while (0)

// accumulate with f32 weights (self-loop)
#define ACC_EDGE_F(w0_, w1_, w2_, w3_, r) do { \
    ls0 += w0_; ls1 += w1_; ls2 += w2_; ls3 += w3_; \
    float xv_[8]; \
    xv_[0] = braw2f((r).x & 0xffff); xv_[1] = braw2f((r).x >> 16); \
    xv_[2] = braw2f((r).y & 0xffff); xv_[3] = braw2f((r).y >> 16); \
    xv_[4] = braw2f((r).z & 0xffff); xv_[5] = braw2f((r).z >> 16); \
    xv_[6] = braw2f((r).w & 0xffff); xv_[7] = braw2f((r).w >> 16); \
    _Pragma("unroll") \
    for (int q_ = 0; q_ < 8; ++q_) { \
        G0[q_] = fmaf(w0_, xv_[q_], G0[q_]); \
        G1[q_] = fmaf(w1_, xv_[q_], G1[q_]); \
        G2[q_] = fmaf(w2_, xv_[q_], G2[q_]); \
        G3[q_] = fmaf(w3_, xv_[q_], G3[q_]); \
    } \
} while (0)

// ---------- fused gather + zgemm over degree-sorted perm (R5-proven config) ----
// Block = 512 threads = 8 waves = 32 perm-consecutive nodes. 4-deep loop,
// VGPR ~60. Self-loop handled inline (prologue) — CSR holds real edges only.
__global__ __launch_bounds__(512) void fused_gz_kernel(const int* __restrict__ perm,
                                                       const int* __restrict__ offs,
                                                       const int* __restrict__ cnt,
                                                       const uint4* __restrict__ eslots,
                                                       const u16* __restrict__ xb,
                                                       const u16* __restrict__ Wfrag,
                                                       const float* __restrict__ a_src,
                                                       const float* __restrict__ a_dst,
                                                       const float* __restrict__ bias,
                                                       float* __restrict__ out,
                                                       int N, int ET) {
    __shared__ u16 smem[32 * 520];
    __shared__ int pvals[32];

    int tid = threadIdx.x;
    int wid = tid >> 6;
    int l = tid & 63;
    int g = l >> 4, c = l & 15, kc = c * 8;
    int n = wid * 4 + g;                 // local node 0..31
    int pidx = blockIdx.x * 32 + n;

    int v = -1;
    if (pidx < N) {
        v = perm[pidx];
        if (v < 0 || v >= N) v = -1;     // defensive
    }
    if (c == 0) pvals[n] = v;

    float ls0 = 0.f, ls1 = 0.f, ls2 = 0.f, ls3 = 0.f;
    float G0[8] = {0,0,0,0,0,0,0,0};
    float G1[8] = {0,0,0,0,0,0,0,0};
    float G2[8] = {0,0,0,0,0,0,0,0};
    float G3[8] = {0,0,0,0,0,0,0,0};

    int beg = 0, end = 0;
    if (v >= 0) {
        beg = offs[v];
        int deg = cnt[v];
        beg = max(0, min(beg, ET));
        end = max(beg, min(beg + deg, ET));

        // self-loop (prologue): weight from logits, own row
        float4 as = ((const float4*)a_src)[v];
        float4 ad = ((const float4*)a_dst)[v];
        float sw0 = __expf(lrelu(as.x + ad.x));
        float sw1 = __expf(lrelu(as.y + ad.y));
        float sw2 = __expf(lrelu(as.z + ad.z));
        float sw3 = __expf(lrelu(as.w + ad.w));
        uint4 rs = *(const uint4*)(xb + (size_t)v * IN_DIM + kc);
        ACC_EDGE_F(sw0, sw1, sw2, sw3, rs);
    }

    // ---- gather phase ----
    int j = beg;
    for (; j + 4 <= end; j += 4) {
        uint4 m0 = eslots[j];
        uint4 m1 = eslots[j + 1];
        uint4 m2 = eslots[j + 2];
        uint4 m3 = eslots[j + 3];
        int s0 = max(0, min((int)m0.x, N - 1));
        int s1 = max(0, min((int)m1.x, N - 1));
        int s2 = max(0, min((int)m2.x, N - 1));
        int s3 = max(0, min((int)m3.x, N - 1));
        uint4 r0 = *(const uint4*)(xb + (size_t)s0 * IN_DIM + kc);
        uint4 r1 = *(const uint4*)(xb + (size_t)s1 * IN_DIM + kc);
        uint4 r2 = *(const uint4*)(xb + (size_t)s2 * IN_DIM + kc);
        uint4 r3 = *(const uint4*)(xb + (size_t)s3 * IN_DIM + kc);
        ACC_EDGE(m0.y, m0.z, r0);
        ACC_EDGE(m1.y, m1.z, r1);
        ACC_EDGE(m2.y, m2.z, r2);
        ACC_EDGE(m3.y, m3.z, r3);
    }
    for (; j < end; ++j) {
        uint4 m0 = eslots[j];
        int s0 = max(0, min((int)m0.x, N - 1));
        uint4 r0 = *(const uint4*)(xb + (size_t)s0 * IN_DIM + kc);
        ACC_EDGE(m0.y, m0.z, r0);
    }

    if (v >= 0) {
        float i0 = 1.f / (ls0 + EPSF), i1 = 1.f / (ls1 + EPSF);
        float i2 = 1.f / (ls2 + EPSF), i3 = 1.f / (ls3 + EPSF);
        u16* lp = smem + n * 520 + c * 8;
        #pragma unroll
        for (int h = 0; h < 4; ++h) {
            const float* G = h == 0 ? G0 : h == 1 ? G1 : h == 2 ? G2 : G3;
            float inv = h == 0 ? i0 : h == 1 ? i1 : h == 2 ? i2 : i3;
            uint4 u;
            u.x = (unsigned)f2braw(G[0] * inv) | ((unsigned)f2braw(G[1] * inv) << 16);
            u.y = (unsigned)f2braw(G[2] * inv) | ((unsigned)f2braw(G[3] * inv) << 16);
            u.z = (unsigned)f2braw(G[4] * inv) | ((unsigned)f2braw(G[5] * inv) << 16);
            u.w = (unsigned)f2braw(G[6] * inv) | ((unsigned)f2braw(G[7] * inv) << 16);
            *(uint4*)(lp + h * 128) = u;
        }
    } else {
        u16* lp = smem + n * 520 + c * 8;
        uint4 z = {0, 0, 0, 0};
        #pragma unroll
        for (int h = 0; h < 4; ++h) *(uint4*)(lp + h * 128) = z;
    }
    __syncthreads();

    // ---- zgemm phase ----
    int t = wid >> 2;                    // tile 0/1 (16 nodes each)
    int h = wid & 3;                     // head
    int q = l >> 4, mcol = l & 15;

    const u16* lp = smem + (t * 16 + mcol) * 520 + h * 128 + q * 8;
    bf16x8 A[4];
    A[0] = *(const bf16x8*)(lp);
    A[1] = *(const bf16x8*)(lp + 32);
    A[2] = *(const bf16x8*)(lp + 64);
    A[3] = *(const bf16x8*)(lp + 96);

    f32x4 acc0 = {0.f,0.f,0.f,0.f}, acc1 = acc0, acc2 = acc0, acc3 = acc0;
    #pragma unroll
    for (int s = 0; s < 4; ++s) {
        const u16* wb = Wfrag + (((h * 4 + s) * 4) << 9) + l * 8;
        bf16x8 B0 = *(const bf16x8*)(wb);
        bf16x8 B1 = *(const bf16x8*)(wb + 512);
        bf16x8 B2 = *(const bf16x8*)(wb + 1024);
        bf16x8 B3 = *(const bf16x8*)(wb + 1536);
        acc0 = __builtin_amdgcn_mfma_f32_16x16x32_bf16(A[s], B0, acc0, 0, 0, 0);
        acc1 = __builtin_amdgcn_mfma_f32_16x16x32_bf16(A[s], B1, acc1, 0, 0, 0);
        acc2 = __builtin_amdgcn_mfma_f32_16x16x32_bf16(A[s], B2, acc2, 0, 0, 0);
        acc3 = __builtin_amdgcn_mfma_f32_16x16x32_bf16(A[s], B3, acc3, 0, 0, 0);
    }

    #pragma unroll
    for (int bt = 0; bt < 4; ++bt) {
        f32x4 a = bt == 0 ? acc0 : bt == 1 ? acc1 : bt == 2 ? acc2 : acc3;
        float b = bias[h * OUT_DIM + bt * 16 + mcol];
        #pragma unroll
        for (int r = 0; r < 4; ++r) {
            int vv = pvals[t * 16 + q * 4 + r];
            if (vv >= 0) {
                float z = a[r] + b;
                float y = z > 0.f ? z : 0.5f * z + 0.5f * (__expf(z) - 1.f);
                out[(size_t)vv * HF + h * OUT_DIM + bt * 16 + mcol] = y;
            }
        }
    }
}

// ---------- fallback gather (4-way, inline exp; self-loop inline) ----------
__global__ __launch_bounds__(512) void gather_bf_kernel(const int* __restrict__ offs,
                                                        const int* __restrict__ cnt,
                                                        const int* __restrict__ slots,
                                                        const u16* __restrict__ xb,
                                                        const float* __restrict__ a_src,
                                                        const float* __restrict__ a_dst,
                                                        u16* __restrict__ Gout, int N, int ET) {
    int v = (blockIdx.x * 512 + threadIdx.x) >> 6;
    int l = threadIdx.x & 63;
    if (v >= N) return;
    int h = l >> 4, c = l & 15, kc = c * 8;

    int beg = offs[v];
    int deg = cnt[v];
    beg = max(0, min(beg, ET));
    int end = max(beg, min(beg + deg, ET));
    float adh = a_dst[v * HEADS + h];

    float ls = 0.f;
    float G[8] = {0.f,0.f,0.f,0.f,0.f,0.f,0.f,0.f};

    // self-loop inline
    {
        float w0 = __expf(lrelu(a_src[v * HEADS + h] + adh));
        uint4 r0 = *(const uint4*)(xb + (size_t)v * IN_DIM + kc);
        ls += w0;
        unsigned ua[4]; ua[0]=r0.x; ua[1]=r0.y; ua[2]=r0.z; ua[3]=r0.w;
        #pragma unroll
        for (int q = 0; q < 4; ++q) {
            G[2*q]   = fmaf(w0, braw2f(ua[q] & 0xffff), G[2*q]);
            G[2*q+1] = fmaf(w0, braw2f(ua[q] >> 16),    G[2*q+1]);
        }
    }

    int j = beg;
    for (; j + 4 <= end; j += 4) {
        int s0 = max(0, min(slots[j],     N - 1));
        int s1 = max(0, min(slots[j + 1], N - 1));
        int s2 = max(0, min(slots[j + 2], N - 1));
        int s3 = max(0, min(slots[j + 3], N - 1));
        float w0 = __expf(lrelu(a_src[s0 * HEADS + h] + adh));
        float w1 = __expf(lrelu(a_src[s1 * HEADS + h] + adh));
        float w2 = __expf(lrelu(a_src[s2 * HEADS + h] + adh));
        float w3 = __expf(lrelu(a_src[s3 * HEADS + h] + adh));
        uint4 r0 = *(const uint4*)(xb + (size_t)s0 * IN_DIM + kc);
        uint4 r1 = *(const uint4*)(xb + (size_t)s1 * IN_DIM + kc);
        uint4 r2 = *(const uint4*)(xb + (size_t)s2 * IN_DIM + kc);
        uint4 r3 = *(const uint4*)(xb + (size_t)s3 * IN_DIM + kc);
        ls += (w0 + w1) + (w2 + w3);
        unsigned ua[4];
        ua[0]=r0.x; ua[1]=r0.y; ua[2]=r0.z; ua[3]=r0.w;
        #pragma unroll
        for (int q = 0; q < 4; ++q) {
            G[2*q]   = fmaf(w0, braw2f(ua[q] & 0xffff), G[2*q]);
            G[2*q+1] = fmaf(w0, braw2f(ua[q] >> 16),    G[2*q+1]);
        }
        ua[0]=r1.x; ua[1]=r1.y; ua[2]=r1.z; ua[3]=r1.w;
        #pragma unroll
        for (int q = 0; q < 4; ++q) {
            G[2*q]   = fmaf(w1, braw2f(ua[q] & 0xffff), G[2*q]);
            G[2*q+1] = fmaf(w1, braw2f(ua[q] >> 16),    G[2*q+1]);
        }
        ua[0]=r2.x; ua[1]=r2.y; ua[2]=r2.z; ua[3]=r2.w;
        #pragma unroll
        for (int q = 0; q < 4; ++q) {
            G[2*q]   = fmaf(w2, braw2f(ua[q] & 0xffff), G[2*q]);
            G[2*q+1] = fmaf(w2, braw2f(ua[q] >> 16),    G[2*q+1]);
        }
        ua[0]=r3.x; ua[1]=r3.y; ua[2]=r3.z; ua[3]=r3.w;
        #pragma unroll
        for (int q = 0; q < 4; ++q) {
            G[2*q]   = fmaf(w3, braw2f(ua[q] & 0xffff), G[2*q]);
            G[2*q+1] = fmaf(w3, braw2f(ua[q] >> 16),    G[2*q+1]);
        }
    }
    for (; j < end; ++j) {
        int s0 = max(0, min(slots[j], N - 1));
        float w0 = __expf(lrelu(a_src[s0 * HEADS + h] + adh));
        uint4 r0 = *(const uint4*)(xb + (size_t)s0 * IN_DIM + kc);
        ls += w0;
        unsigned ua[4]; ua[0]=r0.x; ua[1]=r0.y; ua[2]=r0.z; ua[3]=r0.w;
        #pragma unroll
        for (int q = 0; q < 4; ++q) {
            G[2*q]   = fmaf(w0, braw2f(ua[q] & 0xffff), G[2*q]);
            G[2*q+1] = fmaf(w0, braw2f(ua[q] >> 16),    G[2*q+1]);
        }
    }

    float inv = 1.f / (ls + EPSF);
    uint4 u;
    u.x = (unsigned)f2braw(G[0] * inv) | ((unsigned)f2braw(G[1] * inv) << 16);
    u.y = (unsigned)f2braw(G[2] * inv) | ((unsigned)f2braw(G[3] * inv) << 16);
    u.z = (unsigned)f2braw(G[4] * inv) | ((unsigned)f2braw(G[5] * inv) << 16);
    u.w = (unsigned)f2braw(G[6] * inv) | ((unsigned)f2braw(G[7] * inv) << 16);
    *(uint4*)(Gout + (size_t)v * 512 + h * 128 + kc) = u;
}

// fp32-x fallback (if ws too small for xb; self-loop inline)
__global__ __launch_bounds__(512) void gather_f32_kernel(const int* __restrict__ offs,
                                                         const int* __restrict__ cnt,
                                                         const int* __restrict__ slots,
                                                         const float* __restrict__ x,
                                                         const float* __restrict__ a_src,
                                                         const float* __restrict__ a_dst,
                                                         u16* __restrict__ Gout, int N, int ET) {
    int v = (blockIdx.x * 512 + threadIdx.x) >> 6;
    int l = threadIdx.x & 63;
    if (v >= N) return;
    int h = l >> 4, c = l & 15, kc = c * 8;

    int beg = offs[v];
    int deg = cnt[v];
    beg = max(0, min(beg, ET));
    int end = max(beg, min(beg + deg, ET));
    float adh = a_dst[v * HEADS + h];

    float ls = 0.f;
    float G[8] = {0.f,0.f,0.f,0.f,0.f,0.f,0.f,0.f};

    // self-loop inline
    {
        float w0 = __expf(lrelu(a_src[v * HEADS + h] + adh));
        const float4* xr0 = (const float4*)(x + (size_t)v * IN_DIM + kc);
        float4 a0 = xr0[0], b0 = xr0[1];
        ls += w0;
        G[0]=fmaf(w0,a0.x,G[0]); G[1]=fmaf(w0,a0.y,G[1]);
        G[2]=fmaf(w0,a0.z,G[2]); G[3]=fmaf(w0,a0.w,G[3]);
        G[4]=fmaf(w0,b0.x,G[4]); G[5]=fmaf(w0,b0.y,G[5]);
        G[6]=fmaf(w0,b0.z,G[6]); G[7]=fmaf(w0,b0.w,G[7]);
    }

    for (int j = beg; j < end; ++j) {
        int s0 = max(0, min(slots[j], N - 1));
        float w0 = __expf(lrelu(a_src[s0 * HEADS + h] + adh));
        const float4* xr0 = (const float4*)(x + (size_t)s0 * IN_DIM + kc);
        float4 a0 = xr0[0], b0 = xr0[1];
        ls += w0;
        G[0]=fmaf(w0,a0.x,G[0]); G[1]=fmaf(w0,a0.y,G[1]);
        G[2]=fmaf(w0,a0.z,G[2]); G[3]=fmaf(w0,a0.w,G[3]);
        G[4]=fmaf(w0,b0.x,G[4]); G[5]=fmaf(w0,b0.y,G[5]);
        G[6]=fmaf(w0,b0.z,G[6]); G[7]=fmaf(w0,b0.w,G[7]);
    }
    float inv = 1.f / (ls + EPSF);
    uint4 u;
    u.x = (unsigned)f2braw(G[0] * inv) | ((unsigned)f2braw(G[1] * inv) << 16);
    u.y = (unsigned)f2braw(G[2] * inv) | ((unsigned)f2braw(G[3] * inv) << 16);
    u.z = (unsigned)f2braw(G[4] * inv) | ((unsigned)f2braw(G[5] * inv) << 16);
    u.w = (unsigned)f2braw(G[6] * inv) | ((unsigned)f2braw(G[7] * inv) << 16);
    *(uint4*)(Gout + (size_t)v * 512 + h * 128 + kc) = u;
}

// ---------- standalone zgemm (fallback paths only) ----------
__global__ __launch_bounds__(256) void zgemm_kernel(const u16* __restrict__ Wfrag,
                                                    const float* __restrict__ bias,
                                                    float* __restrict__ out, int N) {
    int h = threadIdx.x >> 6;
    int l = threadIdx.x & 63;
    int q = l >> 4, mcol = l & 15;
    int nb = blockIdx.x * 16;

    const u16* G = (const u16*)out;
    bool valid = (nb + mcol) < N;
    int vA = valid ? nb + mcol : N - 1;
    const u16* gp = G + (size_t)vA * 512 + h * 128 + q * 8;
    bf16x8 A[4];
    A[0] = *(const bf16x8*)(gp);
    A[1] = *(const bf16x8*)(gp + 32);
    A[2] = *(const bf16x8*)(gp + 64);
    A[3] = *(const bf16x8*)(gp + 96);
    if (!valid) {
        bf16x8 zz = {0,0,0,0,0,0,0,0};
        A[0] = zz; A[1] = zz; A[2] = zz; A[3] = zz;
    }

    f32x4 acc0 = {0.f,0.f,0.f,0.f}, acc1 = acc0, acc2 = acc0, acc3 = acc0;
    #pragma unroll
    for (int s = 0; s < 4; ++s) {
        const u16* wb = Wfrag + (((h * 4 + s) * 4) << 9) + l * 8;
        bf16x8 B0 = *(const bf16x8*)(wb);
        bf16x8 B1 = *(const bf16x8*)(wb + 512);
        bf16x8 B2 = *(const bf16x8*)(wb + 1024);
        bf16x8 B3 = *(const bf16x8*)(wb + 1536);
        acc0 = __builtin_amdgcn_mfma_f32_16x16x32_bf16(A[s], B0, acc0, 0, 0, 0);
        acc1 = __builtin_amdgcn_mfma_f32_16x16x32_bf16(A[s], B1, acc1, 0, 0, 0);
        acc2 = __builtin_amdgcn_mfma_f32_16x16x32_bf16(A[s], B2, acc2, 0, 0, 0);
        acc3 = __builtin_amdgcn_mfma_f32_16x16x32_bf16(A[s], B3, acc3, 0, 0, 0);
    }

    #pragma unroll
    for (int t = 0; t < 4; ++t) {
        f32x4 a = t == 0 ? acc0 : t == 1 ? acc1 : t == 2 ? acc2 : acc3;
        float b = bias[h * OUT_DIM + t * 16 + mcol];
        #pragma unroll
        for (int r = 0; r < 4; ++r) {
            int v = nb + q * 4 + r;
            if (v < N) {
                float z = a[r] + b;
                float y = z > 0.f ? z : 0.5f * z + 0.5f * (__expf(z) - 1.f);
                out[(size_t)v * HF + h * OUT_DIM + t * 16 + mcol] = y;
            }
        }
    }
}

extern "C" void kernel_launch(void* const* d_in, const int* in_sizes, int n_in,
                              void* d_out, int out_size, void* d_ws, size_t ws_size,
                              hipStream_t stream) {
    const float* x       = (const float*)d_in[0];
    const int*   ei      = (const int*)d_in[1];
    const float* W       = (const float*)d_in[2];
    const float* att_src = (const float*)d_in[3];
    const float* att_dst = (const float*)d_in[4];
    const float* bias    = (const float*)d_in[5];

    const int N = in_sizes[0] / IN_DIM;   // 50000
    const int E = in_sizes[1] / 2;        // 800000
    const int ET = E + N;                 // CSR capacity (defensive)
    const int NT = (N + 255) / 256;

    // ws: wa_s | wa_d | Wfrag | a_src | a_dst | offs | cnt4(4N) | cur | gcnt |
    //     hist | bcur | perm | slots | xb | eslots(ET*16) | einfo(E*16)
    char* ws = (char*)d_ws;
    size_t off = 0;
    float* wa_s   = (float*)(ws + off); off += HEADS * IN_DIM * 4;
    float* wa_d   = (float*)(ws + off); off += HEADS * IN_DIM * 4;
    u16*   Wfrag  = (u16*)(ws + off);   off += 32768 * 2;
    float* a_src  = (float*)(ws + off); off += (size_t)N * HEADS * 4;
    float* a_dst  = (float*)(ws + off); off += (size_t)N * HEADS * 4;
    int*   offs   = (int*)(ws + off);   off += ((size_t)N * 4 + 15) & ~(size_t)15;
    size_t zero_beg = off;                // start of region to zero
    int*   cnt4   = (int*)(ws + off);   off += ((size_t)N * 16 + 15) & ~(size_t)15;
    int*   cur    = (int*)(ws + off);   off += ((size_t)N * 4 + 15) & ~(size_t)15;
    int*   gcnt   = (int*)(ws + off);   off += 64;
    int*   hist   = (int*)(ws + off);   off += 256 * 4;
    int*   bcur   = (int*)(ws + off);   off += 256 * 4;
    size_t zero_end = off;                // end of region to zero
    int*   perm   = (int*)(ws + off);   off += ((size_t)N * 4 + 15) & ~(size_t)15;
    int*   slots  = (int*)(ws + off);   off += ((size_t)ET * 4 + 15) & ~(size_t)15;
    u16*   xb     = (u16*)(ws + off);   size_t need_bf = off + (size_t)N * IN_DIM * 2;
    unsigned* eslots = (unsigned*)(ws + need_bf);
    size_t need_w = need_bf + (size_t)ET * 16;
    int*   einfo  = (int*)(ws + need_w);
    size_t need_pos = need_w + (size_t)E * 16;
    bool use_bf  = (ws_size >= need_bf);
    bool use_w   = (ws_size >= need_w);
    bool use_pos = (ws_size >= need_pos) && use_w;

    const int NA = (N + 15) / 16;         // logit blocks: 16 nodes/block
    const int NC = (E + 255) / 256;       // count / fill blocks (real edges only)

    // zero cnt4|cur|gcnt|hist|bcur in one stream-ordered memset (graph-safe).
    hipMemsetAsync(ws + zero_beg, 0, zero_end - zero_beg, stream);
    init_kernel<<<1, 256, 0, stream>>>(W, att_src, att_dst, wa_s, wa_d);
    phase1_kernel<<<NA + NC + 8, 256, 0, stream>>>(x, ei, W, wa_s, wa_d, a_src, a_dst,
                                                   use_bf ? xb : (u16*)d_out,
                                                   Wfrag, cnt4,
                                                   use_pos ? einfo : (int*)0,
                                                   N, E, NA, NC);
    offset_kernel<<<NT, 256, 0, stream>>>(cnt4, offs, gcnt, hist, N);
    fillscatter_kernel<<<NC + (use_w ? NT : 0), 256, 0, stream>>>(
        ei, offs, cur, slots, use_w ? eslots : (unsigned*)0, a_src, a_dst,
        cnt4, hist, bcur, perm,
        use_pos ? einfo : (int*)0,
        E, N, NC);
    if (use_w) {
        fused_gz_kernel<<<(N + 31) / 32, 512, 0, stream>>>(perm, offs, cnt4,
                                                           (const uint4*)eslots,
                                                           xb, Wfrag, a_src, a_dst,
                                                           bias, (float*)d_out, N, ET);
    } else if (use_bf) {
        gather_bf_kernel<<<(N * 64 + 511) / 512, 512, 0, stream>>>(offs, cnt4, slots, xb,
                                                                   a_src, a_dst,
                                                                   (u16*)d_out, N, ET);
        zgemm_kernel<<<(N + 15) / 16, 256, 0, stream>>>(Wfrag, bias, (float*)d_out, N);
    } else {
        gather_f32_kernel<<<(N * 64 + 511) / 512, 512, 0, stream>>>(offs, cnt4, slots, x,
                                                                    a_src, a_dst,
                                                                    (u16*)d_out, N, ET);
        zgemm_kernel<<<(N + 15) / 16, 256, 0, stream>>>(Wfrag, bias, (float*)d_out, N);
    }
}

// Round 14
// 234.386 us; speedup vs baseline: 1.0754x; 1.0754x over previous
//
#include <hip/hip_runtime.h>
#include <hip/hip_bf16.h>

typedef unsigned short u16;
typedef __attribute__((ext_vector_type(8))) short bf16x8;
typedef __attribute__((ext_vector_type(4))) float f32x4;
typedef __attribute__((ext_vector_type(4))) int i32x4;

#define HEADS 4
#define OUT_DIM 64
#define HF 256          // HEADS*OUT_DIM
#define IN_DIM 128
#define NEG_SLOPE 0.2f
#define EPSF 1e-16f

__device__ __forceinline__ float braw2f(u16 u) {
    union { float f; unsigned int i; } c; c.i = ((unsigned int)u) << 16; return c.f;
}
__device__ __forceinline__ u16 f2braw(float v) {
    __hip_bfloat16 t = __float2bfloat16(v);
    return *(u16*)&t;
}
__device__ __forceinline__ float lrelu(float e) { return e < 0.f ? NEG_SLOPE * e : e; }

// edge_index contract says int32; defend against raw int64 (odd words all-zero).
__device__ __forceinline__ bool detect_i64(const int* ei) {
    return (ei[1] | ei[3] | ei[5] | ei[7] | ei[9] | ei[11] | ei[13] | ei[15]) == 0;
}

// ---------- init: fold wa = W*att only (zeroing via hipMemsetAsync) ----
__global__ __launch_bounds__(256) void init_kernel(const float* __restrict__ W,
                                                   const float* __restrict__ att_s,
                                                   const float* __restrict__ att_d,
                                                   float* __restrict__ wa_s,
                                                   float* __restrict__ wa_d) {
    for (int idx = threadIdx.x; idx < HEADS * IN_DIM; idx += 256) {
        int h = idx >> 7, k = idx & 127;
        float ss = 0.f, sd = 0.f;
        for (int f = 0; f < OUT_DIM; ++f) {
            float wv = W[k * HF + h * OUT_DIM + f];
            ss = fmaf(wv, att_s[h * OUT_DIM + f], ss);
            sd = fmaf(wv, att_d[h * OUT_DIM + f], sd);
        }
        wa_s[idx] = ss;
        wa_d[idx] = sd;
    }
}

// ---------- phase1: [0,NA) logits + x->bf16 | [NA,NA+NC) count | tail Wfrag ----
// Count (real edges only; self-loops handled inline in gather): 4-way
// replicated counters; atomic's return value + decoded edge recorded in ONE
// 16-B einfo record (plain store — L2-resident producer->consumer handoff;
// NT hint regressed: fill/gather re-read from HBM, phase1 60->67us).
__global__ __launch_bounds__(256) void phase1_kernel(const float* __restrict__ x,
                                                     const int* __restrict__ ei,
                                                     const float* __restrict__ W,
                                                     const float* __restrict__ wa_s,
                                                     const float* __restrict__ wa_d,
                                                     float* __restrict__ a_src,
                                                     float* __restrict__ a_dst,
                                                     u16* __restrict__ xb,
                                                     u16* __restrict__ Wfrag,
                                                     int* __restrict__ cnt4,
                                                     int* __restrict__ einfo,
                                                     int N, int E, int NA, int NC) {
    int b = blockIdx.x;
    if (b < NA) {
        int wid = threadIdx.x >> 6;
        int l = threadIdx.x & 63;
        int g = l >> 4, c = l & 15, kc = c * 8;
        int v = b * 16 + wid * 4 + g;
        if (v >= N) return;

        const float4* xr = (const float4*)(x + (size_t)v * IN_DIM + kc);
        float4 x0 = xr[0], x1 = xr[1];

        uint4 u;
        u.x = (unsigned)f2braw(x0.x) | ((unsigned)f2braw(x0.y) << 16);
        u.y = (unsigned)f2braw(x0.z) | ((unsigned)f2braw(x0.w) << 16);
        u.z = (unsigned)f2braw(x1.x) | ((unsigned)f2braw(x1.y) << 16);
        u.w = (unsigned)f2braw(x1.z) | ((unsigned)f2braw(x1.w) << 16);
        *(uint4*)(xb + (size_t)v * IN_DIM + kc) = u;

        float ps[4], pd[4];
        #pragma unroll
        for (int h = 0; h < 4; ++h) {
            const float4* s4 = (const float4*)(wa_s + h * IN_DIM + kc);
            const float4* d4 = (const float4*)(wa_d + h * IN_DIM + kc);
            float4 s0 = s4[0], s1 = s4[1], d0 = d4[0], d1 = d4[1];
            ps[h] = x0.x*s0.x + x0.y*s0.y + x0.z*s0.z + x0.w*s0.w
                  + x1.x*s1.x + x1.y*s1.y + x1.z*s1.z + x1.w*s1.w;
            pd[h] = x0.x*d0.x + x0.y*d0.y + x0.z*d0.z + x0.w*d0.w
                  + x1.x*d1.x + x1.y*d1.y + x1.z*d1.z + x1.w*d1.w;
        }
        #pragma unroll
        for (int off = 1; off < 16; off <<= 1) {
            #pragma unroll
            for (int h = 0; h < 4; ++h) {
                ps[h] += __shfl_xor(ps[h], off);
                pd[h] += __shfl_xor(pd[h], off);
            }
        }
        if (c == 0) {
            float4 vs, vd;
            vs.x = ps[0]; vs.y = ps[1]; vs.z = ps[2]; vs.w = ps[3];
            vd.x = pd[0]; vd.y = pd[1]; vd.z = pd[2]; vd.w = pd[3];
            *(float4*)(a_src + (size_t)v * HEADS) = vs;
            *(float4*)(a_dst + (size_t)v * HEADS) = vd;
        }
    } else if (b < NA + NC) {
        int t = (b - NA) * 256 + threadIdx.x;
        if (t >= E) return;                 // self-loops handled inline in gather
        bool i64 = detect_i64(ei);
        int src, dst;
        if (i64) { src = ei[2 * t]; dst = ei[2 * (E + t)]; }
        else     { src = ei[t];     dst = ei[E + t]; }
        bool ok = (src >= 0 && src < N && dst >= 0 && dst < N);
        int pos = 0;
        if (ok) pos = atomicAdd(cnt4 + (t & 3) * N + dst, 1);
        if (einfo) {
            i32x4 rec;
            rec.x = ok ? src : -1;
            rec.y = ok ? dst : 0;
            rec.z = pos;
            rec.w = 0;
            *(i32x4*)(einfo + 4 * (size_t)t) = rec;
        }
    } else {
        int bb = b - NA - NC;   // 8 blocks
        for (int idx = bb * 256 + threadIdx.x; idx < 32768; idx += 8 * 256) {
            int j = idx & 7, l = (idx >> 3) & 63, t = (idx >> 9) & 3;
            int s = (idx >> 11) & 3, h = (idx >> 13) & 3;
            int k = s * 32 + ((l >> 4) & 3) * 8 + j;
            int col = h * OUT_DIM + t * 16 + (l & 15);
            Wfrag[idx] = f2braw(W[k * HF + col]);
        }
    }
}

// ---------- order-free offsets + degree histogram + replica bases ----------
__global__ __launch_bounds__(256) void offset_kernel(int* __restrict__ cnt4,
                                                     int* __restrict__ offs,
                                                     int* __restrict__ gcnt,
                                                     int* __restrict__ hist, int N) {
    __shared__ int lh[256];
    lh[threadIdx.x] = 0;
    __syncthreads();

    int idx = blockIdx.x * 256 + threadIdx.x;
    int l = threadIdx.x & 63;
    int d = 0;
    if (idx < N) {
        int c0 = cnt4[idx];
        int c1 = cnt4[N + idx];
        int c2 = cnt4[2 * N + idx];
        int c3 = cnt4[3 * N + idx];
        d = c0 + c1 + c2 + c3;
        cnt4[idx] = d;
        cnt4[N + idx] = c0;
        cnt4[2 * N + idx] = c0 + c1;
        cnt4[3 * N + idx] = c0 + c1 + c2;
        atomicAdd(lh + min(max(d, 0), 255), 1);
    }

    int s = d;
    #pragma unroll
    for (int off = 1; off < 64; off <<= 1) {
        int t = __shfl_up(s, off);
        if (l >= off) s += t;
    }
    int base = 0;
    if (l == 63) base = atomicAdd(gcnt, s);
    base = __shfl(base, 63);
    if (idx < N) offs[idx] = base + s - d;

    __syncthreads();
    if (lh[threadIdx.x]) atomicAdd(hist + threadIdx.x, lh[threadIdx.x]);
}

// ---------- fused fill + scatter ----------
// Fill: atomic-free on the einfo path (one 16-B load per edge); writes one
// 16-B eslots record per edge (plain stores — L2 handoff to gather).
__global__ __launch_bounds__(256) void fillscatter_kernel(const int* __restrict__ ei,
                                                          const int* __restrict__ offs,
                                                          int* __restrict__ cur,
                                                          int* __restrict__ slots,
                                                          unsigned* __restrict__ eslots,
                                                          const float* __restrict__ a_src,
                                                          const float* __restrict__ a_dst,
                                                          const int* __restrict__ cnt4,
                                                          const int* __restrict__ hist,
                                                          int* __restrict__ bcur,
                                                          int* __restrict__ perm,
                                                          const int* __restrict__ einfo,
                                                          int E, int N, int NC) {
    __shared__ int sc[256];
    __shared__ int lh[256];
    __shared__ int lbase[256];

    int b = blockIdx.x;
    if (b < NC) {
        // ---- fill ----
        int t = b * 256 + threadIdx.x;
        if (t >= E) return;
        int src, dst, idx;
        if (einfo) {
            i32x4 rec = *(const i32x4*)(einfo + 4 * (size_t)t);
            src = rec.x; dst = rec.y;
            if (src < 0) return;
            int r = t & 3;
            int base = (r == 0) ? 0 : cnt4[r * N + dst];
            idx = offs[dst] + base + rec.z;
        } else {
            bool i64 = detect_i64(ei);
            if (i64) { src = ei[2 * t]; dst = ei[2 * (E + t)]; }
            else     { src = ei[t];     dst = ei[E + t]; }
            if (!(src >= 0 && src < N && dst >= 0 && dst < N)) return;
            int pos = atomicAdd(cur + dst, 1);
            idx = offs[dst] + pos;
        }
        if (eslots) {
            float4 as = ((const float4*)a_src)[src];
            float4 ad = ((const float4*)a_dst)[dst];
            float w0 = __expf(lrelu(as.x + ad.x));
            float w1 = __expf(lrelu(as.y + ad.y));
            float w2 = __expf(lrelu(as.z + ad.z));
            float w3 = __expf(lrelu(as.w + ad.w));
            i32x4 rec;
            rec.x = src;
            rec.y = (int)((unsigned)f2braw(w0) | ((unsigned)f2braw(w1) << 16));
            rec.z = (int)((unsigned)f2braw(w2) | ((unsigned)f2braw(w3) << 16));
            rec.w = 0;
            *(i32x4*)(eslots + 4 * (size_t)idx) = rec;
        } else {
            slots[idx] = src;
        }
    } else {
        // ---- scatter (with in-block hist scan) ----
        int tid = threadIdx.x;
        sc[tid] = hist[tid];
        lh[tid] = 0;
        __syncthreads();
        #pragma unroll
        for (int off = 1; off < 256; off <<= 1) {
            int tv = (tid >= off) ? sc[tid - off] : 0;
            __syncthreads();
            sc[tid] += tv;
            __syncthreads();
        }

        int idx = (b - NC) * 256 + tid;
        int bk = 0, mypos = 0;
        bool valid = (idx < N);
        if (valid) {
            bk = min(max(cnt4[idx], 0), 255);
            mypos = atomicAdd(lh + bk, 1);
        }
        __syncthreads();
        int c = lh[tid];
        if (c) lbase[tid] = atomicAdd(bcur + tid, c);
        __syncthreads();
        if (valid) {
            int p = (N - sc[bk]) + lbase[bk] + mypos;
            if (p >= 0 && p < N) perm[p] = idx;
        }
    }
}

// accumulate one edge (packed bf16 weights) into the 4-head G registers
#define ACC_EDGE(w01, w23, r) do { \
    float w0_ = braw2f((w01) & 0xffff), w1_ = braw2f((unsigned)(w01) >> 16); \
    float w2_ = braw2f((w23) & 0xffff), w3_ = braw2f((unsigned)(w23) >> 16); \
    ls0 += w0_; ls1 += w1_; ls2 += w2_; ls3 += w3_; \
    float xv_[8]; \
    xv_[0] = braw2f((r).x & 0xffff); xv_[1] = braw2f((r).x >> 16); \
    xv_[2] = braw2f((r).y & 0xffff); xv_[3] = braw2f((r).y >> 16); \
    xv_[4] = braw2f((r).z & 0xffff); xv_[5] = braw2f((r).z >> 16); \
    xv_[6] = braw2f((r).w & 0xffff); xv_[7] = braw2f((r).w >> 16); \
    _Pragma("unroll") \
    for (int q_ = 0; q_ < 8; ++q_) { \
        G0[q_] = fmaf(w0_, xv_[q_], G0[q_]); \
        G1[q_] = fmaf(w1_, xv_[q_], G1[q_]); \
        G2[q_] = fmaf(w2_, xv_[q_], G2[q_]); \
        G3[q_] = fmaf(w3_, xv_[q_], G3[q_]); \
    } \
} while (0)

// accumulate with f32 weights (self-loop)
#define ACC_EDGE_F(w0_, w1_, w2_, w3_, r) do { \
    ls0 += w0_; ls1 += w1_; ls2 += w2_; ls3 += w3_; \
    float xv_[8]; \
    xv_[0] = braw2f((r).x & 0xffff); xv_[1] = braw2f((r).x >> 16); \
    xv_[2] = braw2f((r).y & 0xffff); xv_[3] = braw2f((r).y >> 16); \
    xv_[4] = braw2f((r).z & 0xffff); xv_[5] = braw2f((r).z >> 16); \
    xv_[6] = braw2f((r).w & 0xffff); xv_[7] = braw2f((r).w >> 16); \
    _Pragma("unroll") \
    for (int q_ = 0; q_ < 8; ++q_) { \
        G0[q_] = fmaf(w0_, xv_[q_], G0[q_]); \
        G1[q_] = fmaf(w1_, xv_[q_], G1[q_]); \
        G2[q_] = fmaf(w2_, xv_[q_], G2[q_]); \
        G3[q_] = fmaf(w3_, xv_[q_], G3[q_]); \
    } \
} while (0)

// ---------- fused gather + zgemm over degree-sorted perm (R5-proven config) ----
// Block = 512 threads = 8 waves = 32 perm-consecutive nodes. 4-deep loop.
// Self-loop handled inline (prologue) — CSR holds real edges only.
__global__ __launch_bounds__(512) void fused_gz_kernel(const int* __restrict__ perm,
                                                       const int* __restrict__ offs,
                                                       const int* __restrict__ cnt,
                                                       const uint4* __restrict__ eslots,
                                                       const u16* __restrict__ xb,
                                                       const u16* __restrict__ Wfrag,
                                                       const float* __restrict__ a_src,
                                                       const float* __restrict__ a_dst,
                                                       const float* __restrict__ bias,
                                                       float* __restrict__ out,
                                                       int N, int ET) {
    __shared__ u16 smem[32 * 520];
    __shared__ int pvals[32];

    int tid = threadIdx.x;
    int wid = tid >> 6;
    int l = tid & 63;
    int g = l >> 4, c = l & 15, kc = c * 8;
    int n = wid * 4 + g;                 // local node 0..31
    int pidx = blockIdx.x * 32 + n;

    int v = -1;
    if (pidx < N) {
        v = perm[pidx];
        if (v < 0 || v >= N) v = -1;     // defensive
    }
    if (c == 0) pvals[n] = v;

    float ls0 = 0.f, ls1 = 0.f, ls2 = 0.f, ls3 = 0.f;
    float G0[8] = {0,0,0,0,0,0,0,0};
    float G1[8] = {0,0,0,0,0,0,0,0};
    float G2[8] = {0,0,0,0,0,0,0,0};
    float G3[8] = {0,0,0,0,0,0,0,0};

    int beg = 0, end = 0;
    if (v >= 0) {
        beg = offs[v];
        int deg = cnt[v];
        beg = max(0, min(beg, ET));
        end = max(beg, min(beg + deg, ET));

        // self-loop (prologue): weight from logits, own row
        float4 as = ((const float4*)a_src)[v];
        float4 ad = ((const float4*)a_dst)[v];
        float sw0 = __expf(lrelu(as.x + ad.x));
        float sw1 = __expf(lrelu(as.y + ad.y));
        float sw2 = __expf(lrelu(as.z + ad.z));
        float sw3 = __expf(lrelu(as.w + ad.w));
        uint4 rs = *(const uint4*)(xb + (size_t)v * IN_DIM + kc);
        ACC_EDGE_F(sw0, sw1, sw2, sw3, rs);
    }

    // ---- gather phase ----
    int j = beg;
    for (; j + 4 <= end; j += 4) {
        uint4 m0 = eslots[j];
        uint4 m1 = eslots[j + 1];
        uint4 m2 = eslots[j + 2];
        uint4 m3 = eslots[j + 3];
        int s0 = max(0, min((int)m0.x, N - 1));
        int s1 = max(0, min((int)m1.x, N - 1));
        int s2 = max(0, min((int)m2.x, N - 1));
        int s3 = max(0, min((int)m3.x, N - 1));
        uint4 r0 = *(const uint4*)(xb + (size_t)s0 * IN_DIM + kc);
        uint4 r1 = *(const uint4*)(xb + (size_t)s1 * IN_DIM + kc);
        uint4 r2 = *(const uint4*)(xb + (size_t)s2 * IN_DIM + kc);
        uint4 r3 = *(const uint4*)(xb + (size_t)s3 * IN_DIM + kc);
        ACC_EDGE(m0.y, m0.z, r0);
        ACC_EDGE(m1.y, m1.z, r1);
        ACC_EDGE(m2.y, m2.z, r2);
        ACC_EDGE(m3.y, m3.z, r3);
    }
    for (; j < end; ++j) {
        uint4 m0 = eslots[j];
        int s0 = max(0, min((int)m0.x, N - 1));
        uint4 r0 = *(const uint4*)(xb + (size_t)s0 * IN_DIM + kc);
        ACC_EDGE(m0.y, m0.z, r0);
    }

    if (v >= 0) {
        float i0 = 1.f / (ls0 + EPSF), i1 = 1.f / (ls1 + EPSF);
        float i2 = 1.f / (ls2 + EPSF), i3 = 1.f / (ls3 + EPSF);
        u16* lp = smem + n * 520 + c * 8;
        #pragma unroll
        for (int h = 0; h < 4; ++h) {
            const float* G = h == 0 ? G0 : h == 1 ? G1 : h == 2 ? G2 : G3;
            float inv = h == 0 ? i0 : h == 1 ? i1 : h == 2 ? i2 : i3;
            uint4 u;
            u.x = (unsigned)f2braw(G[0] * inv) | ((unsigned)f2braw(G[1] * inv) << 16);
            u.y = (unsigned)f2braw(G[2] * inv) | ((unsigned)f2braw(G[3] * inv) << 16);
            u.z = (unsigned)f2braw(G[4] * inv) | ((unsigned)f2braw(G[5] * inv) << 16);
            u.w = (unsigned)f2braw(G[6] * inv) | ((unsigned)f2braw(G[7] * inv) << 16);
            *(uint4*)(lp + h * 128) = u;
        }
    } else {
        u16* lp = smem + n * 520 + c * 8;
        uint4 z = {0, 0, 0, 0};
        #pragma unroll
        for (int h = 0; h < 4; ++h) *(uint4*)(lp + h * 128) = z;
    }
    __syncthreads();

    // ---- zgemm phase ----
    int t = wid >> 2;                    // tile 0/1 (16 nodes each)
    int h = wid & 3;                     // head
    int q = l >> 4, mcol = l & 15;

    const u16* lp = smem + (t * 16 + mcol) * 520 + h * 128 + q * 8;
    bf16x8 A[4];
    A[0] = *(const bf16x8*)(lp);
    A[1] = *(const bf16x8*)(lp + 32);
    A[2] = *(const bf16x8*)(lp + 64);
    A[3] = *(const bf16x8*)(lp + 96);

    f32x4 acc0 = {0.f,0.f,0.f,0.f}, acc1 = acc0, acc2 = acc0, acc3 = acc0;
    #pragma unroll
    for (int s = 0; s < 4; ++s) {
        const u16* wb = Wfrag + (((h * 4 + s) * 4) << 9) + l * 8;
        bf16x8 B0 = *(const bf16x8*)(wb);
        bf16x8 B1 = *(const bf16x8*)(wb + 512);
        bf16x8 B2 = *(const bf16x8*)(wb + 1024);
        bf16x8 B3 = *(const bf16x8*)(wb + 1536);
        acc0 = __builtin_amdgcn_mfma_f32_16x16x32_bf16(A[s], B0, acc0, 0, 0, 0);
        acc1 = __builtin_amdgcn_mfma_f32_16x16x32_bf16(A[s], B1, acc1, 0, 0, 0);
        acc2 = __builtin_amdgcn_mfma_f32_16x16x32_bf16(A[s], B2, acc2, 0, 0, 0);
        acc3 = __builtin_amdgcn_mfma_f32_16x16x32_bf16(A[s], B3, acc3, 0, 0, 0);
    }

    #pragma unroll
    for (int bt = 0; bt < 4; ++bt) {
        f32x4 a = bt == 0 ? acc0 : bt == 1 ? acc1 : bt == 2 ? acc2 : acc3;
        float b = bias[h * OUT_DIM + bt * 16 + mcol];
        #pragma unroll
        for (int r = 0; r < 4; ++r) {
            int vv = pvals[t * 16 + q * 4 + r];
            if (vv >= 0) {
                float z = a[r] + b;
                float y = z > 0.f ? z : 0.5f * z + 0.5f * (__expf(z) - 1.f);
                out[(size_t)vv * HF + h * OUT_DIM + bt * 16 + mcol] = y;
            }
        }
    }
}

// ---------- fallback gather (4-way, inline exp; self-loop inline) ----------
__global__ __launch_bounds__(512) void gather_bf_kernel(const int* __restrict__ offs,
                                                        const int* __restrict__ cnt,
                                                        const int* __restrict__ slots,
                                                        const u16* __restrict__ xb,
                                                        const float* __restrict__ a_src,
                                                        const float* __restrict__ a_dst,
                                                        u16* __restrict__ Gout, int N, int ET) {
    int v = (blockIdx.x * 512 + threadIdx.x) >> 6;
    int l = threadIdx.x & 63;
    if (v >= N) return;
    int h = l >> 4, c = l & 15, kc = c * 8;

    int beg = offs[v];
    int deg = cnt[v];
    beg = max(0, min(beg, ET));
    int end = max(beg, min(beg + deg, ET));
    float adh = a_dst[v * HEADS + h];

    float ls = 0.f;
    float G[8] = {0.f,0.f,0.f,0.f,0.f,0.f,0.f,0.f};

    // self-loop inline
    {
        float w0 = __expf(lrelu(a_src[v * HEADS + h] + adh));
        uint4 r0 = *(const uint4*)(xb + (size_t)v * IN_DIM + kc);
        ls += w0;
        unsigned ua[4]; ua[0]=r0.x; ua[1]=r0.y; ua[2]=r0.z; ua[3]=r0.w;
        #pragma unroll
        for (int q = 0; q < 4; ++q) {
            G[2*q]   = fmaf(w0, braw2f(ua[q] & 0xffff), G[2*q]);
            G[2*q+1] = fmaf(w0, braw2f(ua[q] >> 16),    G[2*q+1]);
        }
    }

    int j = beg;
    for (; j + 4 <= end; j += 4) {
        int s0 = max(0, min(slots[j],     N - 1));
        int s1 = max(0, min(slots[j + 1], N - 1));
        int s2 = max(0, min(slots[j + 2], N - 1));
        int s3 = max(0, min(slots[j + 3], N - 1));
        float w0 = __expf(lrelu(a_src[s0 * HEADS + h] + adh));
        float w1 = __expf(lrelu(a_src[s1 * HEADS + h] + adh));
        float w2 = __expf(lrelu(a_src[s2 * HEADS + h] + adh));
        float w3 = __expf(lrelu(a_src[s3 * HEADS + h] + adh));
        uint4 r0 = *(const uint4*)(xb + (size_t)s0 * IN_DIM + kc);
        uint4 r1 = *(const uint4*)(xb + (size_t)s1 * IN_DIM + kc);
        uint4 r2 = *(const uint4*)(xb + (size_t)s2 * IN_DIM + kc);
        uint4 r3 = *(const uint4*)(xb + (size_t)s3 * IN_DIM + kc);
        ls += (w0 + w1) + (w2 + w3);
        unsigned ua[4];
        ua[0]=r0.x; ua[1]=r0.y; ua[2]=r0.z; ua[3]=r0.w;
        #pragma unroll
        for (int q = 0; q < 4; ++q) {
            G[2*q]   = fmaf(w0, braw2f(ua[q] & 0xffff), G[2*q]);
            G[2*q+1] = fmaf(w0, braw2f(ua[q] >> 16),    G[2*q+1]);
        }
        ua[0]=r1.x; ua[1]=r1.y; ua[2]=r1.z; ua[3]=r1.w;
        #pragma unroll
        for (int q = 0; q < 4; ++q) {
            G[2*q]   = fmaf(w1, braw2f(ua[q] & 0xffff), G[2*q]);
            G[2*q+1] = fmaf(w1, braw2f(ua[q] >> 16),    G[2*q+1]);
        }
        ua[0]=r2.x; ua[1]=r2.y; ua[2]=r2.z; ua[3]=r2.w;
        #pragma unroll
        for (int q = 0; q < 4; ++q) {
            G[2*q]   = fmaf(w2, braw2f(ua[q] & 0xffff), G[2*q]);
            G[2*q+1] = fmaf(w2, braw2f(ua[q] >> 16),    G[2*q+1]);
        }
        ua[0]=r3.x; ua[1]=r3.y; ua[2]=r3.z; ua[3]=r3.w;
        #pragma unroll
        for (int q = 0; q < 4; ++q) {
            G[2*q]   = fmaf(w3, braw2f(ua[q] & 0xffff), G[2*q]);
            G[2*q+1] = fmaf(w3, braw2f(ua[q] >> 16),    G[2*q+1]);
        }
    }
    for (; j < end; ++j) {
        int s0 = max(0, min(slots[j], N - 1));
        float w0 = __expf(lrelu(a_src[s0 * HEADS + h] + adh));
        uint4 r0 = *(const uint4*)(xb + (size_t)s0 * IN_DIM + kc);
        ls += w0;
        unsigned ua[4]; ua[0]=r0.x; ua[1]=r0.y; ua[2]=r0.z; ua[3]=r0.w;
        #pragma unroll
        for (int q = 0; q < 4; ++q) {
            G[2*q]   = fmaf(w0, braw2f(ua[q] & 0xffff), G[2*q]);
            G[2*q+1] = fmaf(w0, braw2f(ua[q] >> 16),    G[2*q+1]);
        }
    }

    float inv = 1.f / (ls + EPSF);
    uint4 u;
    u.x = (unsigned)f2braw(G[0] * inv) | ((unsigned)f2braw(G[1] * inv) << 16);
    u.y = (unsigned)f2braw(G[2] * inv) | ((unsigned)f2braw(G[3] * inv) << 16);
    u.z = (unsigned)f2braw(G[4] * inv) | ((unsigned)f2braw(G[5] * inv) << 16);
    u.w = (unsigned)f2braw(G[6] * inv) | ((unsigned)f2braw(G[7] * inv) << 16);
    *(uint4*)(Gout + (size_t)v * 512 + h * 128 + kc) = u;
}

// fp32-x fallback (if ws too small for xb; self-loop inline)
__global__ __launch_bounds__(512) void gather_f32_kernel(const int* __restrict__ offs,
                                                         const int* __restrict__ cnt,
                                                         const int* __restrict__ slots,
                                                         const float* __restrict__ x,
                                                         const float* __restrict__ a_src,
                                                         const float* __restrict__ a_dst,
                                                         u16* __restrict__ Gout, int N, int ET) {
    int v = (blockIdx.x * 512 + threadIdx.x) >> 6;
    int l = threadIdx.x & 63;
    if (v >= N) return;
    int h = l >> 4, c = l & 15, kc = c * 8;

    int beg = offs[v];
    int deg = cnt[v];
    beg = max(0, min(beg, ET));
    int end = max(beg, min(beg + deg, ET));
    float adh = a_dst[v * HEADS + h];

    float ls = 0.f;
    float G[8] = {0.f,0.f,0.f,0.f,0.f,0.f,0.f,0.f};

    // self-loop inline
    {
        float w0 = __expf(lrelu(a_src[v * HEADS + h] + adh));
        const float4* xr0 = (const float4*)(x + (size_t)v * IN_DIM + kc);
        float4 a0 = xr0[0], b0 = xr0[1];
        ls += w0;
        G[0]=fmaf(w0,a0.x,G[0]); G[1]=fmaf(w0,a0.y,G[1]);
        G[2]=fmaf(w0,a0.z,G[2]); G[3]=fmaf(w0,a0.w,G[3]);
        G[4]=fmaf(w0,b0.x,G[4]); G[5]=fmaf(w0,b0.y,G[5]);
        G[6]=fmaf(w0,b0.z,G[6]); G[7]=fmaf(w0,b0.w,G[7]);
    }

    for (int j = beg; j < end; ++j) {
        int s0 = max(0, min(slots[j], N - 1));
        float w0 = __expf(lrelu(a_src[s0 * HEADS + h] + adh));
        const float4* xr0 = (const float4*)(x + (size_t)s0 * IN_DIM + kc);
        float4 a0 = xr0[0], b0 = xr0[1];
        ls += w0;
        G[0]=fmaf(w0,a0.x,G[0]); G[1]=fmaf(w0,a0.y,G[1]);
        G[2]=fmaf(w0,a0.z,G[2]); G[3]=fmaf(w0,a0.w,G[3]);
        G[4]=fmaf(w0,b0.x,G[4]); G[5]=fmaf(w0,b0.y,G[5]);
        G[6]=fmaf(w0,b0.z,G[6]); G[7]=fmaf(w0,b0.w,G[7]);
    }
    float inv = 1.f / (ls + EPSF);
    uint4 u;
    u.x = (unsigned)f2braw(G[0] * inv) | ((unsigned)f2braw(G[1] * inv) << 16);
    u.y = (unsigned)f2braw(G[2] * inv) | ((unsigned)f2braw(G[3] * inv) << 16);
    u.z = (unsigned)f2braw(G[4] * inv) | ((unsigned)f2braw(G[5] * inv) << 16);
    u.w = (unsigned)f2braw(G[6] * inv) | ((unsigned)f2braw(G[7] * inv) << 16);
    *(uint4*)(Gout + (size_t)v * 512 + h * 128 + kc) = u;
}

// ---------- standalone zgemm (fallback paths only) ----------
__global__ __launch_bounds__(256) void zgemm_kernel(const u16* __restrict__ Wfrag,
                                                    const float* __restrict__ bias,
                                                    float* __restrict__ out, int N) {
    int h = threadIdx.x >> 6;
    int l = threadIdx.x & 63;
    int q = l >> 4, mcol = l & 15;
    int nb = blockIdx.x * 16;

    const u16* G = (const u16*)out;
    bool valid = (nb + mcol) < N;
    int vA = valid ? nb + mcol : N - 1;
    const u16* gp = G + (size_t)vA * 512 + h * 128 + q * 8;
    bf16x8 A[4];
    A[0] = *(const bf16x8*)(gp);
    A[1] = *(const bf16x8*)(gp + 32);
    A[2] = *(const bf16x8*)(gp + 64);
    A[3] = *(const bf16x8*)(gp + 96);
    if (!valid) {
        bf16x8 zz = {0,0,0,0,0,0,0,0};
        A[0] = zz; A[1] = zz; A[2] = zz; A[3] = zz;
    }

    f32x4 acc0 = {0.f,0.f,0.f,0.f}, acc1 = acc0, acc2 = acc0, acc3 = acc0;
    #pragma unroll
    for (int s = 0; s < 4; ++s) {
        const u16* wb = Wfrag + (((h * 4 + s) * 4) << 9) + l * 8;
        bf16x8 B0 = *(const bf16x8*)(wb);
        bf16x8 B1 = *(const bf16x8*)(wb + 512);
        bf16x8 B2 = *(const bf16x8*)(wb + 1024);
        bf16x8 B3 = *(const bf16x8*)(wb + 1536);
        acc0 = __builtin_amdgcn_mfma_f32_16x16x32_bf16(A[s], B0, acc0, 0, 0, 0);
        acc1 = __builtin_amdgcn_mfma_f32_16x16x32_bf16(A[s], B1, acc1, 0, 0, 0);
        acc2 = __builtin_amdgcn_mfma_f32_16x16x32_bf16(A[s], B2, acc2, 0, 0, 0);
        acc3 = __builtin_amdgcn_mfma_f32_16x16x32_bf16(A[s], B3, acc3, 0, 0, 0);
    }

    #pragma unroll
    for (int t = 0; t < 4; ++t) {
        f32x4 a = t == 0 ? acc0 : t == 1 ? acc1 : t == 2 ? acc2 : acc3;
        float b = bias[h * OUT_DIM + t * 16 + mcol];
        #pragma unroll
        for (int r = 0; r < 4; ++r) {
            int v = nb + q * 4 + r;
            if (v < N) {
                float z = a[r] + b;
                float y = z > 0.f ? z : 0.5f * z + 0.5f * (__expf(z) - 1.f);
                out[(size_t)v * HF + h * OUT_DIM + t * 16 + mcol] = y;
            }
        }
    }
}

extern "C" void kernel_launch(void* const* d_in, const int* in_sizes, int n_in,
                              void* d_out, int out_size, void* d_ws, size_t ws_size,
                              hipStream_t stream) {
    const float* x       = (const float*)d_in[0];
    const int*   ei      = (const int*)d_in[1];
    const float* W       = (const float*)d_in[2];
    const float* att_src = (const float*)d_in[3];
    const float* att_dst = (const float*)d_in[4];
    const float* bias    = (const float*)d_in[5];

    const int N = in_sizes[0] / IN_DIM;   // 50000
    const int E = in_sizes[1] / 2;        // 800000
    const int ET = E + N;                 // CSR capacity (defensive)
    const int NT = (N + 255) / 256;

    // ws: wa_s | wa_d | Wfrag | a_src | a_dst | offs | cnt4(4N) | cur | gcnt |
    //     hist | bcur | perm | slots | xb | eslots(ET*16) | einfo(E*16)
    char* ws = (char*)d_ws;
    size_t off = 0;
    float* wa_s   = (float*)(ws + off); off += HEADS * IN_DIM * 4;
    float* wa_d   = (float*)(ws + off); off += HEADS * IN_DIM * 4;
    u16*   Wfrag  = (u16*)(ws + off);   off += 32768 * 2;
    float* a_src  = (float*)(ws + off); off += (size_t)N * HEADS * 4;
    float* a_dst  = (float*)(ws + off); off += (size_t)N * HEADS * 4;
    int*   offs   = (int*)(ws + off);   off += ((size_t)N * 4 + 15) & ~(size_t)15;
    size_t zero_beg = off;                // start of region to zero
    int*   cnt4   = (int*)(ws + off);   off += ((size_t)N * 16 + 15) & ~(size_t)15;
    int*   cur    = (int*)(ws + off);   off += ((size_t)N * 4 + 15) & ~(size_t)15;
    int*   gcnt   = (int*)(ws + off);   off += 64;
    int*   hist   = (int*)(ws + off);   off += 256 * 4;
    int*   bcur   = (int*)(ws + off);   off += 256 * 4;
    size_t zero_end = off;                // end of region to zero
    int*   perm   = (int*)(ws + off);   off += ((size_t)N * 4 + 15) & ~(size_t)15;
    int*   slots  = (int*)(ws + off);   off += ((size_t)ET * 4 + 15) & ~(size_t)15;
    u16*   xb     = (u16*)(ws + off);   size_t need_bf = off + (size_t)N * IN_DIM * 2;
    unsigned* eslots = (unsigned*)(ws + need_bf);
    size_t need_w = need_bf + (size_t)ET * 16;
    int*   einfo  = (int*)(ws + need_w);
    size_t need_pos = need_w + (size_t)E * 16;
    bool use_bf  = (ws_size >= need_bf);
    bool use_w   = (ws_size >= need_w);
    bool use_pos = (ws_size >= need_pos) && use_w;

    const int NA = (N + 15) / 16;         // logit blocks: 16 nodes/block
    const int NC = (E + 255) / 256;       // count / fill blocks (real edges only)

    // zero cnt4|cur|gcnt|hist|bcur in one stream-ordered memset (graph-safe).
    hipMemsetAsync(ws + zero_beg, 0, zero_end - zero_beg, stream);
    init_kernel<<<1, 256, 0, stream>>>(W, att_src, att_dst, wa_s, wa_d);
    phase1_kernel<<<NA + NC + 8, 256, 0, stream>>>(x, ei, W, wa_s, wa_d, a_src, a_dst,
                                                   use_bf ? xb : (u16*)d_out,
                                                   Wfrag, cnt4,
                                                   use_pos ? einfo : (int*)0,
                                                   N, E, NA, NC);
    offset_kernel<<<NT, 256, 0, stream>>>(cnt4, offs, gcnt, hist, N);
    fillscatter_kernel<<<NC + (use_w ? NT : 0), 256, 0, stream>>>(
        ei, offs, cur, slots, use_w ? eslots : (unsigned*)0, a_src, a_dst,
        cnt4, hist, bcur, perm,
        use_pos ? einfo : (int*)0,
        E, N, NC);
    if (use_w) {
        fused_gz_kernel<<<(N + 31) / 32, 512, 0, stream>>>(perm, offs, cnt4,
                                                           (const uint4*)eslots,
                                                           xb, Wfrag, a_src, a_dst,
                                                           bias, (float*)d_out, N, ET);
    } else if (use_bf) {
        gather_bf_kernel<<<(N * 64 + 511) / 512, 512, 0, stream>>>(offs, cnt4, slots, xb,
                                                                   a_src, a_dst,
                                                                   (u16*)d_out, N, ET);
        zgemm_kernel<<<(N + 15) / 16, 256, 0, stream>>>(Wfrag, bias, (float*)d_out, N);
    } else {
        gather_f32_kernel<<<(N * 64 + 511) / 512, 512, 0, stream>>>(offs, cnt4, slots, x,
                                                                    a_src, a_dst,
                                                                    (u16*)d_out, N, ET);
        zgemm_kernel<<<(N + 15) / 16, 256, 0, stream>>>(Wfrag, bias, (float*)d_out, N);
    }
}